// Round 2
// baseline (131.298 us; speedup 1.0000x reference)
//
#include <hip/hip_runtime.h>

// Output: diag(d), N x N fp32, where
// d = -params*r_mask + ics_mask + triggers*vcsw_mask + vc_mask
//
// Pure HBM-write-bound: 604 MB per call.
// History:
//   v1: 1 float4 store/thread, 147K blocks        -> 97.3 us (6.21 TB/s)
//   v2: 1 block/row, 12 stores/thread             -> 116.9 us (5.17 TB/s)  REGRESSED
// Post-mortem: v2 scattered the active write front across ~96 MB (2048
// resident blocks x private 48 KB rows) -> DRAM page thrash. The harness's
// fillBufferAligned hits 6.8 TB/s at 11% occupancy with a compact
// grid-stride front. v3 mimics it: flat grid-stride over float4s, whole
// grid resident, all waves sweep a contiguous ~8 MB window together.
// Diagonal membership via constant division per float4 (magic-mul, cheap);
// diag value computed in a rare divergent branch (~1 in 48 wave-iters).
static constexpr int N = 12288;
static constexpr unsigned F4_PER_ROW = N / 4;                    // 3072
static constexpr long long TOTAL_F4 = (long long)N * N / 4;      // 37,748,736
static constexpr int BLOCK = 256;
static constexpr int GRID = 2048;                                // fully resident: 8 blocks/CU
static constexpr unsigned NTHREADS = (unsigned)BLOCK * GRID;     // 524,288
static constexpr int ITERS = (int)(TOTAL_F4 / NTHREADS);         // 72, exact

typedef float vfloat4 __attribute__((ext_vector_type(4)));

__global__ __launch_bounds__(BLOCK)
void impedance_fused_kernel(const float* __restrict__ params,
                            const float* __restrict__ triggers,
                            const float* __restrict__ r_mask,
                            const float* __restrict__ ics_mask,
                            const float* __restrict__ vcsw_mask,
                            const float* __restrict__ vc_mask,
                            float* __restrict__ out) {
    unsigned f = blockIdx.x * (unsigned)BLOCK + threadIdx.x;  // flat float4 index
    vfloat4* __restrict__ o = (vfloat4*)out;
    const vfloat4 zerov = (vfloat4)(0.f);

#pragma unroll 4
    for (int k = 0; k < ITERS; ++k, f += NTHREADS) {
        vfloat4 v = zerov;
        // row = f / 3072 (compiler emits magic-mul), q = f % 3072
        unsigned row = f / F4_PER_ROW;
        unsigned q   = f - row * F4_PER_ROW;
        if (q == (row >> 2)) {
            // Rare (12,288 of 37.7M float4s): this float4 holds (row,row).
            // Inputs are 48 KB each -> L2-resident after first touches.
            float d = fmaf(-params[row], r_mask[row],
                      fmaf(triggers[row], vcsw_mask[row],
                           ics_mask[row] + vc_mask[row]));
            unsigned r3 = row & 3u;
            // Static component writes (no runtime vector index -> no scratch).
            v.x = (r3 == 0u) ? d : 0.f;
            v.y = (r3 == 1u) ? d : 0.f;
            v.z = (r3 == 2u) ? d : 0.f;
            v.w = (r3 == 3u) ? d : 0.f;
        }
        __builtin_nontemporal_store(v, o + f);
    }
}

extern "C" void kernel_launch(void* const* d_in, const int* in_sizes, int n_in,
                              void* d_out, int out_size, void* d_ws, size_t ws_size,
                              hipStream_t stream) {
    const float* params    = (const float*)d_in[0];
    const float* triggers  = (const float*)d_in[1];
    const float* r_mask    = (const float*)d_in[2];
    const float* ics_mask  = (const float*)d_in[3];
    const float* vcsw_mask = (const float*)d_in[4];
    const float* vc_mask   = (const float*)d_in[5];
    float* out = (float*)d_out;

    dim3 grid(GRID, 1, 1);
    dim3 block(BLOCK, 1, 1);
    impedance_fused_kernel<<<grid, block, 0, stream>>>(
        params, triggers, r_mask, ics_mask, vcsw_mask, vc_mask, out);
}

// Round 3
// 111.793 us; speedup vs baseline: 1.1745x; 1.1745x over previous
//
#include <hip/hip_runtime.h>

// Output: diag(d), N x N fp32, where
// d = -params*r_mask + ics_mask + triggers*vcsw_mask + vc_mask
//
// Pure HBM-write-bound: 604 MB per call.
// History:
//   v1: 1 float4/thread, 147K tiny blocks          -> 97.3 us (6.21 TB/s)
//   v2: 1 block/row, 12 stores/thread              -> 116.9 us (5.17 TB/s)
//   v3: grid-stride, 2048 blocks (100% occupancy)  -> 131.3 us (4.60 TB/s)
// Post-mortem: stores don't block, so in v2/v3 every resident wave runs
// ahead independently -> thousands of interleaved write streams at the
// HBM controllers -> burst efficiency collapses. More waves = worse.
// The harness's fillBufferAligned hits 6.8 TB/s at 10.8% OCCUPANCY:
// few streams per CU, each advancing linearly. v4 copies that shape:
// 256 blocks (1/CU, 4 waves/CU, ~12% occupancy), grid-stride, 576
// float4 stores per thread. Diagonal via magic-div compare, rare branch.
static constexpr int N = 12288;
static constexpr unsigned F4_PER_ROW = N / 4;                    // 3072
static constexpr long long TOTAL_F4 = (long long)N * N / 4;      // 37,748,736
static constexpr int BLOCK = 256;
static constexpr int GRID = 256;                                 // 1 block/CU
static constexpr unsigned NTHREADS = (unsigned)BLOCK * GRID;     // 65,536
static constexpr int ITERS = (int)(TOTAL_F4 / NTHREADS);         // 576, exact

typedef float vfloat4 __attribute__((ext_vector_type(4)));

__global__ __launch_bounds__(BLOCK)
void impedance_fused_kernel(const float* __restrict__ params,
                            const float* __restrict__ triggers,
                            const float* __restrict__ r_mask,
                            const float* __restrict__ ics_mask,
                            const float* __restrict__ vcsw_mask,
                            const float* __restrict__ vc_mask,
                            float* __restrict__ out) {
    unsigned f = blockIdx.x * (unsigned)BLOCK + threadIdx.x;  // flat float4 idx
    vfloat4* __restrict__ o = (vfloat4*)out;
    const vfloat4 zerov = (vfloat4)(0.f);

#pragma unroll 4
    for (int k = 0; k < ITERS; ++k, f += NTHREADS) {
        vfloat4 v = zerov;
        // row = f / 3072 (magic-mul), q = f % 3072
        unsigned row = f / F4_PER_ROW;
        unsigned q   = f - row * F4_PER_ROW;
        if (q == (row >> 2)) {
            // Rare (1 float4 in 3072): this float4 holds (row,row).
            // Inputs are 48 KB each -> L2/L3-resident after first touch.
            float d = fmaf(-params[row], r_mask[row],
                      fmaf(triggers[row], vcsw_mask[row],
                           ics_mask[row] + vc_mask[row]));
            unsigned r3 = row & 3u;
            v.x = (r3 == 0u) ? d : 0.f;
            v.y = (r3 == 1u) ? d : 0.f;
            v.z = (r3 == 2u) ? d : 0.f;
            v.w = (r3 == 3u) ? d : 0.f;
        }
        __builtin_nontemporal_store(v, o + f);
    }
}

extern "C" void kernel_launch(void* const* d_in, const int* in_sizes, int n_in,
                              void* d_out, int out_size, void* d_ws, size_t ws_size,
                              hipStream_t stream) {
    const float* params    = (const float*)d_in[0];
    const float* triggers  = (const float*)d_in[1];
    const float* r_mask    = (const float*)d_in[2];
    const float* ics_mask  = (const float*)d_in[3];
    const float* vcsw_mask = (const float*)d_in[4];
    const float* vc_mask   = (const float*)d_in[5];
    float* out = (float*)d_out;

    dim3 grid(GRID, 1, 1);
    dim3 block(BLOCK, 1, 1);
    impedance_fused_kernel<<<grid, block, 0, stream>>>(
        params, triggers, r_mask, ics_mask, vcsw_mask, vc_mask, out);
}

// Round 4
// 102.571 us; speedup vs baseline: 1.2801x; 1.0899x over previous
//
#include <hip/hip_runtime.h>

// Output: diag(d), N x N fp32, where
// d = -params*r_mask + ics_mask + triggers*vcsw_mask + vc_mask
//
// Pure HBM-write-bound: 604 MB per call.
// History:
//   v1: 1 float4/thread, 147K tiny blocks          -> 97.3 us (6.21 TB/s)
//   v2: 1 block/row, 12 stores/thread              -> 116.9 us (5.17 TB/s)
//   v3: grid-stride, 2048 blocks (100% occ)        -> 131.3 us (4.60 TB/s)
//   v4: grid-stride, 256 blocks (12% occ)          -> 111.8 us (5.40 TB/s)
// Post-mortem: no hand-written store loop shape matched the runtime's
// __amd_rocclr_fillBufferAligned, which sustains 6.7-6.87 TB/s in every
// rocprof capture. v5 stops imitating it and invokes it: hipMemsetAsync
// (graph-capturable, stream-ordered) zeroes the 604 MB at the proven fill
// rate, then a tiny kernel writes the 12,288 diagonal elements.
static constexpr int N = 12288;
static constexpr int DIAG_BLOCK = 256;
static constexpr int DIAG_GRID = N / DIAG_BLOCK;   // 48 blocks, 192 waves

__global__ __launch_bounds__(DIAG_BLOCK)
void impedance_diag_kernel(const float* __restrict__ params,
                           const float* __restrict__ triggers,
                           const float* __restrict__ r_mask,
                           const float* __restrict__ ics_mask,
                           const float* __restrict__ vcsw_mask,
                           const float* __restrict__ vc_mask,
                           float* __restrict__ out) {
    const int i = blockIdx.x * DIAG_BLOCK + threadIdx.x;   // 0..N-1
    const float d = fmaf(-params[i], r_mask[i],
                    fmaf(triggers[i], vcsw_mask[i],
                         ics_mask[i] + vc_mask[i]));
    out[(size_t)i * (N + 1)] = d;    // (i, i)
}

extern "C" void kernel_launch(void* const* d_in, const int* in_sizes, int n_in,
                              void* d_out, int out_size, void* d_ws, size_t ws_size,
                              hipStream_t stream) {
    const float* params    = (const float*)d_in[0];
    const float* triggers  = (const float*)d_in[1];
    const float* r_mask    = (const float*)d_in[2];
    const float* ics_mask  = (const float*)d_in[3];
    const float* vcsw_mask = (const float*)d_in[4];
    const float* vc_mask   = (const float*)d_in[5];
    float* out = (float*)d_out;

    // Bulk zero at the runtime fill kernel's proven 6.8 TB/s.
    hipMemsetAsync(out, 0, (size_t)N * N * sizeof(float), stream);

    // Then scatter the 12,288 diagonal values (latency-bound, a few us).
    dim3 grid(DIAG_GRID, 1, 1);
    dim3 block(DIAG_BLOCK, 1, 1);
    impedance_diag_kernel<<<grid, block, 0, stream>>>(
        params, triggers, r_mask, ics_mask, vcsw_mask, vc_mask, out);
}